// Round 1
// baseline (3039.884 us; speedup 1.0000x reference)
//
#include <hip/hip_runtime.h>
#include <hip/hip_bf16.h>
#include <math.h>

// ---------------------------------------------------------------------------
// GATv2 x2 + log_softmax + gated rule-net, fp32 baseline.
// Phases (each its own kernel for profiling):
//   1. gemm: xl1 = x@Wl1, xr1 = x@Wr1          [N,128]
//   2. edge_logits<H=2>: leaky_relu(xl[src]+xr[dst]).att -> logits, atomicMax mx[dst]
//   3. edge_accum<H=2>: ex = exp(logit - mx[dst]); atomicAdd den[dst], agg[dst] += ex*xl[src]
//   4. finalize1: h1 = relu(agg/den + b1)
//   5. gemm: xl2 = h1@Wl2, xr2 = h1@Wr2        [N,64]
//   6-7. edge passes H=1
//   8. final fused: v = agg2/den2 + b2 -> log_softmax -> rule net -> out
// ---------------------------------------------------------------------------

__device__ inline void atomicMaxFloat(float* addr, float val) {
    if (val >= 0.f) atomicMax((int*)addr, __float_as_int(val));
    else            atomicMin((unsigned int*)addr, (unsigned int)__float_as_int(val));
}

__global__ void fill_kernel(float* __restrict__ p, float v, int count) {
    int i = blockIdx.x * blockDim.x + threadIdx.x;
    if (i < count) p[i] = v;
}

// Y[n,M] = X[n,K] @ W[K,M]; one thread per output element.
__global__ void gemm_kernel(const float* __restrict__ X, const float* __restrict__ W,
                            float* __restrict__ Y, int n, int K, int M) {
    int idx = blockIdx.x * blockDim.x + threadIdx.x;
    if (idx >= n * M) return;
    int row = idx / M, col = idx % M;
    const float* xr = X + (size_t)row * K;
    const float* wc = W + col;
    float acc = 0.f;
    #pragma unroll 4
    for (int k = 0; k < K; k++) acc += xr[k] * wc[(size_t)k * M];
    Y[idx] = acc;
}

// 16 lanes per (edge, head). C = 64 channels per head.
template<int H>
__global__ void edge_logits_kernel(const float* __restrict__ xl,
                                   const float* __restrict__ xr,
                                   const int* __restrict__ ei,
                                   const float* __restrict__ att,
                                   float* __restrict__ logits,
                                   float* __restrict__ mx,
                                   int E, int ET) {
    int g = (blockIdx.x * blockDim.x + threadIdx.x) >> 4;
    int lane = threadIdx.x & 15;
    if (g >= ET * H) return;
    int edge = g / H, head = g % H;
    int src, dst;
    if (edge < E) { src = ei[edge]; dst = ei[E + edge]; }
    else          { src = dst = edge - E; }
    const int HC = H * 64;
    float4 a = *(const float4*)(att + head * 64 + lane * 4);
    float4 l = *(const float4*)(xl + (size_t)src * HC + head * 64 + lane * 4);
    float4 r = *(const float4*)(xr + (size_t)dst * HC + head * 64 + lane * 4);
    float p = 0.f;
    {
        float e;
        e = l.x + r.x; e = e > 0.f ? e : 0.2f * e; p += e * a.x;
        e = l.y + r.y; e = e > 0.f ? e : 0.2f * e; p += e * a.y;
        e = l.z + r.z; e = e > 0.f ? e : 0.2f * e; p += e * a.z;
        e = l.w + r.w; e = e > 0.f ? e : 0.2f * e; p += e * a.w;
    }
    #pragma unroll
    for (int o = 8; o; o >>= 1) p += __shfl_xor(p, o, 16);
    if (lane == 0) {
        logits[(size_t)edge * H + head] = p;
        atomicMaxFloat(mx + (size_t)dst * H + head, p);
    }
}

template<int H>
__global__ void edge_accum_kernel(const float* __restrict__ xl,
                                  const int* __restrict__ ei,
                                  const float* __restrict__ logits,
                                  const float* __restrict__ mx,
                                  float* __restrict__ agg,
                                  float* __restrict__ den,
                                  int E, int ET) {
    int g = (blockIdx.x * blockDim.x + threadIdx.x) >> 4;
    int lane = threadIdx.x & 15;
    if (g >= ET * H) return;
    int edge = g / H, head = g % H;
    int src, dst;
    if (edge < E) { src = ei[edge]; dst = ei[E + edge]; }
    else          { src = dst = edge - E; }
    const int HC = H * 64;
    float ex = expf(logits[(size_t)edge * H + head] - mx[(size_t)dst * H + head]);
    float4 l = *(const float4*)(xl + (size_t)src * HC + head * 64 + lane * 4);
    float* base = agg + (size_t)dst * HC + head * 64 + lane * 4;
    atomicAdd(base + 0, ex * l.x);
    atomicAdd(base + 1, ex * l.y);
    atomicAdd(base + 2, ex * l.z);
    atomicAdd(base + 3, ex * l.w);
    if (lane == 0) atomicAdd(den + (size_t)dst * H + head, ex);
}

// h1 = relu(agg/den + b1), in place; layer-1 shape [n, 2*64]
__global__ void finalize1_kernel(float* __restrict__ h, const float* __restrict__ den,
                                 const float* __restrict__ b, int n) {
    int idx = blockIdx.x * blockDim.x + threadIdx.x;
    if (idx >= n * 128) return;
    int node = idx >> 7, c = idx & 127, head = c >> 6;
    float v = h[idx] / (den[node * 2 + head] + 1e-16f) + b[c];
    h[idx] = v > 0.f ? v : 0.f;
}

// One wave (64 lanes) per node: normalize+bias -> log_softmax -> rule net -> out
__global__ __launch_bounds__(256)
void final_kernel(const float* __restrict__ agg2, const float* __restrict__ den2,
                  const float* __restrict__ b2,
                  const float* __restrict__ We1, const float* __restrict__ be1,
                  const float* __restrict__ We2, const float* __restrict__ be2,
                  float* __restrict__ out, int n) {
    __shared__ float sW1[64 * 64], sW2[64 * 64], sb1[64], sb2[64];
    __shared__ float srow[4][64], strow[4][64];
    for (int i = threadIdx.x; i < 64 * 64; i += 256) { sW1[i] = We1[i]; sW2[i] = We2[i]; }
    if (threadIdx.x < 64) { sb1[threadIdx.x] = be1[threadIdx.x]; sb2[threadIdx.x] = be2[threadIdx.x]; }
    __syncthreads();
    int wave = threadIdx.x >> 6, lane = threadIdx.x & 63;
    int node = blockIdx.x * 4 + wave;
    if (node >= n) return;
    float v = agg2[(size_t)node * 64 + lane] / (den2[node] + 1e-16f) + b2[lane];
    float m = v;
    #pragma unroll
    for (int o = 32; o; o >>= 1) m = fmaxf(m, __shfl_xor(m, o));
    float p = expf(v - m);
    float s = p;
    #pragma unroll
    for (int o = 32; o; o >>= 1) s += __shfl_xor(s, o);
    float ls = v - m - logf(s);
    srow[wave][lane] = ls;
    float acc = sb1[lane];
    #pragma unroll 8
    for (int k = 0; k < 64; k++) acc += srow[wave][k] * sW1[k * 64 + lane];
    float t = acc > 0.f ? acc : 0.f;
    strow[wave][lane] = t;
    acc = sb2[lane];
    #pragma unroll 8
    for (int k = 0; k < 64; k++) acc += strow[wave][k] * sW2[k * 64 + lane];
    float g = 1.f / (1.f + expf(-acc));
    out[(size_t)node * 64 + lane] = ls + g;
}

extern "C" void kernel_launch(void* const* d_in, const int* in_sizes, int n_in,
                              void* d_out, int out_size, void* d_ws, size_t ws_size,
                              hipStream_t stream) {
    const float* x    = (const float*)d_in[0];
    const int*   ei   = (const int*)d_in[1];
    const float* Wl1  = (const float*)d_in[2];
    const float* Wr1  = (const float*)d_in[3];
    const float* att1 = (const float*)d_in[4];
    const float* b1   = (const float*)d_in[5];
    const float* Wl2  = (const float*)d_in[6];
    const float* Wr2  = (const float*)d_in[7];
    const float* att2 = (const float*)d_in[8];
    const float* b2   = (const float*)d_in[9];
    const float* We1  = (const float*)d_in[10];
    const float* be1  = (const float*)d_in[11];
    const float* We2  = (const float*)d_in[12];
    const float* be2  = (const float*)d_in[13];
    float* out = (float*)d_out;

    const int n  = in_sizes[0] / 128;
    const int E  = in_sizes[1] / 2;
    const int ET = E + n;

    float* ws = (float*)d_ws;
    size_t o = 0;
    float* xl1     = ws + o; o += (size_t)n * 128;
    float* xr1     = ws + o; o += (size_t)n * 128;
    float* h1      = ws + o; o += (size_t)n * 128;   // agg1, then h1 in place
    float* logits1 = ws + o; o += (size_t)ET * 2;
    float* mx1     = ws + o; o += (size_t)n * 2;
    float* den1    = ws + o; o += (size_t)n * 2;
    // layer-2 aliases (safe: xl1/xr1 regions dead by the time these are written)
    float* xl2     = xl1;                // [n,64]
    float* xr2     = xl1 + (size_t)n * 64;
    float* agg2    = xr1;                // [n,64]
    float* mx2     = xr1 + (size_t)n * 64;
    float* den2    = mx2 + n;
    float* logits2 = logits1;

    const int BS = 256;
    auto blocks = [](long long t, int bs) { return (int)((t + bs - 1) / bs); };

    // ---- layer 1 ----
    gemm_kernel<<<blocks((long long)n * 128, BS), BS, 0, stream>>>(x, Wl1, xl1, n, 128, 128);
    gemm_kernel<<<blocks((long long)n * 128, BS), BS, 0, stream>>>(x, Wr1, xr1, n, 128, 128);
    fill_kernel<<<blocks((long long)n * 128, BS), BS, 0, stream>>>(h1, 0.f, n * 128);
    fill_kernel<<<blocks((long long)n * 2, BS), BS, 0, stream>>>(mx1, -INFINITY, n * 2);
    fill_kernel<<<blocks((long long)n * 2, BS), BS, 0, stream>>>(den1, 0.f, n * 2);
    edge_logits_kernel<2><<<blocks((long long)ET * 2 * 16, BS), BS, 0, stream>>>(
        xl1, xr1, ei, att1, logits1, mx1, E, ET);
    edge_accum_kernel<2><<<blocks((long long)ET * 2 * 16, BS), BS, 0, stream>>>(
        xl1, ei, logits1, mx1, h1, den1, E, ET);
    finalize1_kernel<<<blocks((long long)n * 128, BS), BS, 0, stream>>>(h1, den1, b1, n);

    // ---- layer 2 ----
    gemm_kernel<<<blocks((long long)n * 64, BS), BS, 0, stream>>>(h1, Wl2, xl2, n, 128, 64);
    gemm_kernel<<<blocks((long long)n * 64, BS), BS, 0, stream>>>(h1, Wr2, xr2, n, 128, 64);
    fill_kernel<<<blocks((long long)n * 64, BS), BS, 0, stream>>>(agg2, 0.f, n * 64);
    fill_kernel<<<blocks((long long)n, BS), BS, 0, stream>>>(mx2, -INFINITY, n);
    fill_kernel<<<blocks((long long)n, BS), BS, 0, stream>>>(den2, 0.f, n);
    edge_logits_kernel<1><<<blocks((long long)ET * 16, BS), BS, 0, stream>>>(
        xl2, xr2, ei, att2, logits2, mx2, E, ET);
    edge_accum_kernel<1><<<blocks((long long)ET * 16, BS), BS, 0, stream>>>(
        xl2, ei, logits2, mx2, agg2, den2, E, ET);

    // ---- finalize: log_softmax + rule net ----
    final_kernel<<<blocks(((long long)n + 3) / 4 * 256, BS), BS, 0, stream>>>(
        agg2, den2, b2, We1, be1, We2, be2, out, n);
}

// Round 2
// 522.004 us; speedup vs baseline: 5.8235x; 5.8235x over previous
//
#include <hip/hip_runtime.h>
#include <hip/hip_bf16.h>
#include <math.h>

// ---------------------------------------------------------------------------
// GATv2 x2 + log_softmax + gated rule-net.
// R1: CSR-by-dst + gather-style fused online-softmax aggregation (no float
// atomics), LDS-resident-W GEMMs.
// Pipeline:
//   CSR build: deg(=1 self loop)+hist -> scan -> scatter   (int atomics only)
//   xl1,xr1 = x@Wl1, x@Wr1          (gemm_lds)
//   h1      = node_agg<H=2,relu+bias>(xl1,xr1,csr)          one pass per node
//   xl2,xr2 = h1@Wl2, h1@Wr2
//   v2      = node_agg<H=1,plain>(xl2,xr2,csr)              (normalized, no bias)
//   out     = final(v2 + b2 -> log_softmax -> gate rule net)
// ---------------------------------------------------------------------------

__global__ void fill_int_kernel(int* __restrict__ p, int v, int count) {
    int i = blockIdx.x * blockDim.x + threadIdx.x;
    if (i < count) p[i] = v;
}

__global__ void hist_kernel(const int* __restrict__ ei, int* __restrict__ deg, int E) {
    int e = blockIdx.x * blockDim.x + threadIdx.x;
    if (e < E) atomicAdd(&deg[ei[E + e]], 1);
}

// single-block inclusive scan -> exclusive rowptr[n+1]
__global__ __launch_bounds__(1024)
void scan_kernel(const int* __restrict__ deg, int* __restrict__ rowptr, int n) {
    __shared__ int sdata[1024];
    __shared__ int carry;
    if (threadIdx.x == 0) { carry = 0; rowptr[0] = 0; }
    __syncthreads();
    for (int base = 0; base < n; base += 1024) {
        int i = base + threadIdx.x;
        int v = (i < n) ? deg[i] : 0;
        sdata[threadIdx.x] = v;
        __syncthreads();
        #pragma unroll
        for (int off = 1; off < 1024; off <<= 1) {
            int t = (threadIdx.x >= off) ? sdata[threadIdx.x - off] : 0;
            __syncthreads();
            sdata[threadIdx.x] += t;
            __syncthreads();
        }
        if (i < n) rowptr[i + 1] = carry + sdata[threadIdx.x];
        __syncthreads();
        if (threadIdx.x == 1023) carry += sdata[1023];
        __syncthreads();
    }
}

__global__ void copy_int_kernel(const int* __restrict__ a, int* __restrict__ b, int count) {
    int i = blockIdx.x * blockDim.x + threadIdx.x;
    if (i < count) b[i] = a[i];
}

// scatter edges into CSR slots (order within a row is nondeterministic; only
// affects fp32 summation order at ~1e-6 level)
__global__ void scatter_kernel(const int* __restrict__ ei, int* __restrict__ cursor,
                               int* __restrict__ srcs, int E, int ET) {
    int e = blockIdx.x * blockDim.x + threadIdx.x;
    if (e >= ET) return;
    int src, dst;
    if (e < E) { src = ei[e]; dst = ei[E + e]; }
    else       { src = dst = e - E; }
    int pos = atomicAdd(&cursor[dst], 1);
    srcs[pos] = src;
}

// Y[n,M] = X[n,128] @ W[128,M], W staged in LDS, RB rows per block.
template<int M, int RB>
__global__ __launch_bounds__(256)
void gemm_lds_kernel(const float* __restrict__ X, const float* __restrict__ W,
                     float* __restrict__ Y, int n) {
    constexpr int K = 128;
    constexpr int RGROUPS = 256 / M;   // row-slots per block
    constexpr int RT = RB / RGROUPS;   // rows per thread
    __shared__ float sW[K * M];
    __shared__ float sX[RB][K];
    for (int i = threadIdx.x; i < K * M; i += 256) sW[i] = W[i];
    int row0 = blockIdx.x * RB;
    for (int i = threadIdx.x; i < RB * K / 4; i += 256) {
        int r = i / (K / 4), c4 = i % (K / 4);
        int grow = row0 + r;
        float4 v = (grow < n) ? *(const float4*)(X + (size_t)grow * K + c4 * 4)
                              : make_float4(0.f, 0.f, 0.f, 0.f);
        *(float4*)(&sX[r][c4 * 4]) = v;
    }
    __syncthreads();
    int col = threadIdx.x % M;
    int rslot = threadIdx.x / M;
    float acc[RT] = {};
    for (int k = 0; k < K; ++k) {
        float wv = sW[k * M + col];
        #pragma unroll
        for (int r = 0; r < RT; ++r) acc[r] += sX[rslot * RT + r][k] * wv;
    }
    #pragma unroll
    for (int r = 0; r < RT; ++r) {
        int grow = row0 + rslot * RT + r;
        if (grow < n) Y[(size_t)grow * M + col] = acc[r];
    }
}

// One 16-lane group per (node, head): online softmax over incoming edges.
// Reads each xl[src] row slice exactly once; no atomics.
template<int H, bool RELU_BIAS>
__global__ __launch_bounds__(256)
void node_agg_kernel(const float* __restrict__ xl, const float* __restrict__ xr,
                     const int* __restrict__ rowptr, const int* __restrict__ srcs,
                     const float* __restrict__ att, const float* __restrict__ bias,
                     float* __restrict__ out, int n) {
    int g = (blockIdx.x * blockDim.x + threadIdx.x) >> 4;
    int lane = threadIdx.x & 15;
    if (g >= n * H) return;
    int node = g / H, head = g % H;
    const int HC = H * 64;
    int cbase = head * 64 + lane * 4;
    float4 r4 = *(const float4*)(xr + (size_t)node * HC + cbase);
    float4 a4 = *(const float4*)(att + cbase);
    int start = rowptr[node], end = rowptr[node + 1];
    float m = -INFINITY, d = 0.f;
    float4 acc = make_float4(0.f, 0.f, 0.f, 0.f);
    for (int k = start; k < end; ++k) {
        int src = srcs[k];
        float4 l4 = *(const float4*)(xl + (size_t)src * HC + cbase);
        float e, p = 0.f;
        e = l4.x + r4.x; e = e > 0.f ? e : 0.2f * e; p += e * a4.x;
        e = l4.y + r4.y; e = e > 0.f ? e : 0.2f * e; p += e * a4.y;
        e = l4.z + r4.z; e = e > 0.f ? e : 0.2f * e; p += e * a4.z;
        e = l4.w + r4.w; e = e > 0.f ? e : 0.2f * e; p += e * a4.w;
        #pragma unroll
        for (int o = 8; o; o >>= 1) p += __shfl_xor(p, o, 16);
        float nm = fmaxf(m, p);
        float sc = __expf(m - nm);   // first iter: exp(-inf)=0
        float w  = __expf(p - nm);
        d = d * sc + w;
        acc.x = acc.x * sc + w * l4.x;
        acc.y = acc.y * sc + w * l4.y;
        acc.z = acc.z * sc + w * l4.z;
        acc.w = acc.w * sc + w * l4.w;
        m = nm;
    }
    float inv = 1.f / (d + 1e-16f);
    float4 o4 = make_float4(acc.x * inv, acc.y * inv, acc.z * inv, acc.w * inv);
    if (RELU_BIAS) {
        float4 b4 = *(const float4*)(bias + cbase);
        o4.x = fmaxf(o4.x + b4.x, 0.f);
        o4.y = fmaxf(o4.y + b4.y, 0.f);
        o4.z = fmaxf(o4.z + b4.z, 0.f);
        o4.w = fmaxf(o4.w + b4.w, 0.f);
    }
    *(float4*)(out + (size_t)node * HC + cbase) = o4;
}

// One wave per node: v2+bias -> log_softmax -> rule net -> out
__global__ __launch_bounds__(256)
void final_kernel(const float* __restrict__ v2, const float* __restrict__ b2,
                  const float* __restrict__ We1, const float* __restrict__ be1,
                  const float* __restrict__ We2, const float* __restrict__ be2,
                  float* __restrict__ out, int n) {
    __shared__ float sW1[64 * 64], sW2[64 * 64], sb1[64], sb2[64];
    __shared__ float srow[4][64], strow[4][64];
    for (int i = threadIdx.x; i < 64 * 64; i += 256) { sW1[i] = We1[i]; sW2[i] = We2[i]; }
    if (threadIdx.x < 64) { sb1[threadIdx.x] = be1[threadIdx.x]; sb2[threadIdx.x] = be2[threadIdx.x]; }
    __syncthreads();
    int wave = threadIdx.x >> 6, lane = threadIdx.x & 63;
    int node = blockIdx.x * 4 + wave;
    if (node >= n) return;
    float v = v2[(size_t)node * 64 + lane] + b2[lane];
    float m = v;
    #pragma unroll
    for (int o = 32; o; o >>= 1) m = fmaxf(m, __shfl_xor(m, o));
    float p = expf(v - m);
    float s = p;
    #pragma unroll
    for (int o = 32; o; o >>= 1) s += __shfl_xor(s, o);
    float ls = v - m - logf(s);
    srow[wave][lane] = ls;
    float acc = sb1[lane];
    #pragma unroll 8
    for (int k = 0; k < 64; k++) acc += srow[wave][k] * sW1[k * 64 + lane];
    float t = acc > 0.f ? acc : 0.f;
    strow[wave][lane] = t;
    acc = sb2[lane];
    #pragma unroll 8
    for (int k = 0; k < 64; k++) acc += strow[wave][k] * sW2[k * 64 + lane];
    float g = 1.f / (1.f + expf(-acc));
    out[(size_t)node * 64 + lane] = ls + g;
}

extern "C" void kernel_launch(void* const* d_in, const int* in_sizes, int n_in,
                              void* d_out, int out_size, void* d_ws, size_t ws_size,
                              hipStream_t stream) {
    const float* x    = (const float*)d_in[0];
    const int*   ei   = (const int*)d_in[1];
    const float* Wl1  = (const float*)d_in[2];
    const float* Wr1  = (const float*)d_in[3];
    const float* att1 = (const float*)d_in[4];
    const float* b1   = (const float*)d_in[5];
    const float* Wl2  = (const float*)d_in[6];
    const float* Wr2  = (const float*)d_in[7];
    const float* att2 = (const float*)d_in[8];
    const float* b2   = (const float*)d_in[9];
    const float* We1  = (const float*)d_in[10];
    const float* be1  = (const float*)d_in[11];
    const float* We2  = (const float*)d_in[12];
    const float* be2  = (const float*)d_in[13];
    float* out = (float*)d_out;

    const int n  = in_sizes[0] / 128;
    const int E  = in_sizes[1] / 2;
    const int ET = E + n;

    float* ws = (float*)d_ws;
    size_t o = 0;
    float* xl1 = ws + o; o += (size_t)n * 128;   // later: xl2 [n,64] + xr2 [n,64]
    float* xr1 = ws + o; o += (size_t)n * 128;   // later: v2 [n,64]
    float* h1  = ws + o; o += (size_t)n * 128;
    int* rowptr = (int*)(ws + o); o += (size_t)(n + 1);
    int* cursor = (int*)(ws + o); o += (size_t)n;
    int* srcs   = (int*)(ws + o); o += (size_t)ET;
    float* xl2 = xl1;
    float* xr2 = xl1 + (size_t)n * 64;
    float* v2  = xr1;
    int* deg = cursor;  // deg reuses cursor before scan; cursor re-derived after

    const int BS = 256;
    auto blocks = [](long long t, int bs) { return (int)((t + bs - 1) / bs); };

    // ---- CSR build (by dst), self-loops included via deg init = 1 ----
    fill_int_kernel<<<blocks(n, BS), BS, 0, stream>>>(deg, 1, n);
    hist_kernel<<<blocks(E, BS), BS, 0, stream>>>(ei, deg, E);
    scan_kernel<<<1, 1024, 0, stream>>>(deg, rowptr, n);
    copy_int_kernel<<<blocks(n, BS), BS, 0, stream>>>(rowptr, cursor, n);
    scatter_kernel<<<blocks(ET, BS), BS, 0, stream>>>(ei, cursor, srcs, E, ET);

    // ---- layer 1 ----
    gemm_lds_kernel<128, 32><<<blocks(n, 32), BS, 0, stream>>>(x, Wl1, xl1, n);
    gemm_lds_kernel<128, 32><<<blocks(n, 32), BS, 0, stream>>>(x, Wr1, xr1, n);
    node_agg_kernel<2, true><<<blocks((long long)n * 2 * 16, BS), BS, 0, stream>>>(
        xl1, xr1, rowptr, srcs, att1, b1, h1, n);

    // ---- layer 2 ----
    gemm_lds_kernel<64, 32><<<blocks(n, 32), BS, 0, stream>>>(h1, Wl2, xl2, n);
    gemm_lds_kernel<64, 32><<<blocks(n, 32), BS, 0, stream>>>(h1, Wr2, xr2, n);
    node_agg_kernel<1, false><<<blocks((long long)n * 16, BS), BS, 0, stream>>>(
        xl2, xr2, rowptr, srcs, att2, nullptr, v2, n);

    // ---- finalize: bias + log_softmax + rule net ----
    final_kernel<<<blocks(((long long)n + 3) / 4 * 256, BS), BS, 0, stream>>>(
        v2, b2, We1, be1, We2, be2, out, n);
}

// Round 3
// 427.550 us; speedup vs baseline: 7.1100x; 1.2209x over previous
//
#include <hip/hip_runtime.h>
#include <hip/hip_bf16.h>
#include <math.h>

// ---------------------------------------------------------------------------
// GATv2 x2 + log_softmax + gated rule-net.
// R2: hierarchical scan (was 90us single-block), register-tiled fused
// dual-GEMM (Wl|Wr in one pass, 4 FMA per LDS read).
// ---------------------------------------------------------------------------

__global__ void fill_int_kernel(int* __restrict__ p, int v, int count) {
    int i = blockIdx.x * blockDim.x + threadIdx.x;
    if (i < count) p[i] = v;
}

__global__ void hist_kernel(const int* __restrict__ ei, int* __restrict__ deg, int E) {
    int e = blockIdx.x * blockDim.x + threadIdx.x;
    if (e < E) atomicAdd(&deg[ei[E + e]], 1);
}

// S1: per-block inclusive scan of 1024-elem chunks; rowptr[i+1] = chunk-local
// inclusive sum; partials[b] = chunk total.
__global__ __launch_bounds__(1024)
void scan_block_kernel(const int* __restrict__ deg, int* __restrict__ rowptr,
                       int* __restrict__ partials, int n) {
    __shared__ int s[1024];
    int i = blockIdx.x * 1024 + threadIdx.x;
    int v = (i < n) ? deg[i] : 0;
    s[threadIdx.x] = v;
    __syncthreads();
    #pragma unroll
    for (int off = 1; off < 1024; off <<= 1) {
        int t = (threadIdx.x >= off) ? s[threadIdx.x - off] : 0;
        __syncthreads();
        s[threadIdx.x] += t;
        __syncthreads();
    }
    if (i < n) rowptr[i + 1] = s[threadIdx.x];
    if (threadIdx.x == 1023) partials[blockIdx.x] = s[1023];
}

// S2: single block scans the (<=1024) partials into exclusive offsets.
__global__ __launch_bounds__(1024)
void scan_partials_kernel(int* __restrict__ partials, int nparts) {
    __shared__ int s[1024];
    int v = (threadIdx.x < nparts) ? partials[threadIdx.x] : 0;
    s[threadIdx.x] = v;
    __syncthreads();
    #pragma unroll
    for (int off = 1; off < 1024; off <<= 1) {
        int t = (threadIdx.x >= off) ? s[threadIdx.x - off] : 0;
        __syncthreads();
        s[threadIdx.x] += t;
        __syncthreads();
    }
    if (threadIdx.x < nparts) partials[threadIdx.x] = s[threadIdx.x] - v;  // exclusive
}

// S3: add block offsets; also produce cursor[] (== final rowptr) for scatter.
__global__ __launch_bounds__(1024)
void scan_apply_kernel(int* __restrict__ rowptr, const int* __restrict__ partials,
                       int* __restrict__ cursor, int n) {
    int i = blockIdx.x * 1024 + threadIdx.x;
    if (i == 0) { rowptr[0] = 0; cursor[0] = 0; }
    if (i < n) {
        int val = rowptr[i + 1] + partials[blockIdx.x];
        rowptr[i + 1] = val;
        if (i + 1 < n) cursor[i + 1] = val;
    }
}

// scatter edges into CSR slots
__global__ void scatter_kernel(const int* __restrict__ ei, int* __restrict__ cursor,
                               int* __restrict__ srcs, int E, int ET) {
    int e = blockIdx.x * blockDim.x + threadIdx.x;
    if (e >= ET) return;
    int src, dst;
    if (e < E) { src = ei[e]; dst = ei[E + e]; }
    else       { src = dst = e - E; }
    int pos = atomicAdd(&cursor[dst], 1);
    srcs[pos] = src;
}

// Fused dual GEMM: Y0[n,M] = X[n,128]@W0, Y1[n,M] = X[n,128]@W1, M = MTOT/2.
// Block tile 64 rows x MTOT cols; 256 threads; per-thread 8 rows x (MTOT/32) cols.
template<int MTOT>
__global__ __launch_bounds__(256)
void gemm_dual_kernel(const float* __restrict__ X,
                      const float* __restrict__ W0, const float* __restrict__ W1,
                      float* __restrict__ Y0, float* __restrict__ Y1, int n) {
    constexpr int K = 128, BK = 32, BM = 64;
    constexpr int M = MTOT / 2;
    constexpr int NJ = MTOT / 32;      // cols per thread
    __shared__ float sX[BM][36];       // stride 36: 16B-aligned rows, conflict-free reads
    __shared__ float sW[BK][MTOT];
    int tid = threadIdx.x;
    int cc = tid & 31, rr = tid >> 5;  // col lane, row group
    int row0 = blockIdx.x * BM;
    float acc[8][NJ];
    #pragma unroll
    for (int i = 0; i < 8; i++)
        #pragma unroll
        for (int j = 0; j < NJ; j++) acc[i][j] = 0.f;

    for (int kc = 0; kc < K / BK; ++kc) {
        // stage X tile [64][32]
        #pragma unroll
        for (int t = tid; t < BM * BK / 4; t += 256) {
            int r = t >> 3, c4 = t & 7;
            int grow = row0 + r;
            float4 v = (grow < n) ? *(const float4*)(X + (size_t)grow * K + kc * BK + c4 * 4)
                                  : make_float4(0.f, 0.f, 0.f, 0.f);
            *(float4*)(&sX[r][c4 * 4]) = v;
        }
        // stage W tile [32][MTOT] = [W0 | W1]
        #pragma unroll
        for (int t = tid; t < BK * MTOT / 4; t += 256) {
            int kr = t / (MTOT / 4), m4 = t % (MTOT / 4);
            int m = m4 * 4, gk = kc * BK + kr;
            float4 v = (m < M) ? *(const float4*)(W0 + (size_t)gk * M + m)
                               : *(const float4*)(W1 + (size_t)gk * M + (m - M));
            *(float4*)(&sW[kr][m]) = v;
        }
        __syncthreads();
        #pragma unroll
        for (int k = 0; k < BK; ++k) {
            float a[8], b[NJ];
            #pragma unroll
            for (int i = 0; i < 8; i++) a[i] = sX[rr + 8 * i][k];
            #pragma unroll
            for (int j = 0; j < NJ; j++) b[j] = sW[k][cc + 32 * j];
            #pragma unroll
            for (int i = 0; i < 8; i++)
                #pragma unroll
                for (int j = 0; j < NJ; j++) acc[i][j] += a[i] * b[j];
        }
        __syncthreads();
    }
    #pragma unroll
    for (int i = 0; i < 8; i++) {
        int row = row0 + rr + 8 * i;
        if (row >= n) continue;
        #pragma unroll
        for (int j = 0; j < NJ; j++) {
            int m = cc + 32 * j;
            if (m < M) Y0[(size_t)row * M + m] = acc[i][j];
            else       Y1[(size_t)row * M + (m - M)] = acc[i][j];
        }
    }
}

// One 16-lane group per (node, head): online softmax over incoming edges.
template<int H, bool RELU_BIAS>
__global__ __launch_bounds__(256)
void node_agg_kernel(const float* __restrict__ xl, const float* __restrict__ xr,
                     const int* __restrict__ rowptr, const int* __restrict__ srcs,
                     const float* __restrict__ att, const float* __restrict__ bias,
                     float* __restrict__ out, int n) {
    int g = (blockIdx.x * blockDim.x + threadIdx.x) >> 4;
    int lane = threadIdx.x & 15;
    if (g >= n * H) return;
    int node = g / H, head = g % H;
    const int HC = H * 64;
    int cbase = head * 64 + lane * 4;
    float4 r4 = *(const float4*)(xr + (size_t)node * HC + cbase);
    float4 a4 = *(const float4*)(att + cbase);
    int start = rowptr[node], end = rowptr[node + 1];
    float m = -INFINITY, d = 0.f;
    float4 acc = make_float4(0.f, 0.f, 0.f, 0.f);
    for (int k = start; k < end; ++k) {
        int src = srcs[k];
        float4 l4 = *(const float4*)(xl + (size_t)src * HC + cbase);
        float e, p = 0.f;
        e = l4.x + r4.x; e = e > 0.f ? e : 0.2f * e; p += e * a4.x;
        e = l4.y + r4.y; e = e > 0.f ? e : 0.2f * e; p += e * a4.y;
        e = l4.z + r4.z; e = e > 0.f ? e : 0.2f * e; p += e * a4.z;
        e = l4.w + r4.w; e = e > 0.f ? e : 0.2f * e; p += e * a4.w;
        #pragma unroll
        for (int o = 8; o; o >>= 1) p += __shfl_xor(p, o, 16);
        float nm = fmaxf(m, p);
        float sc = __expf(m - nm);
        float w  = __expf(p - nm);
        d = d * sc + w;
        acc.x = acc.x * sc + w * l4.x;
        acc.y = acc.y * sc + w * l4.y;
        acc.z = acc.z * sc + w * l4.z;
        acc.w = acc.w * sc + w * l4.w;
        m = nm;
    }
    float inv = 1.f / (d + 1e-16f);
    float4 o4 = make_float4(acc.x * inv, acc.y * inv, acc.z * inv, acc.w * inv);
    if (RELU_BIAS) {
        float4 b4 = *(const float4*)(bias + cbase);
        o4.x = fmaxf(o4.x + b4.x, 0.f);
        o4.y = fmaxf(o4.y + b4.y, 0.f);
        o4.z = fmaxf(o4.z + b4.z, 0.f);
        o4.w = fmaxf(o4.w + b4.w, 0.f);
    }
    *(float4*)(out + (size_t)node * HC + cbase) = o4;
}

// One wave per node: v2+bias -> log_softmax -> rule net -> out
__global__ __launch_bounds__(256)
void final_kernel(const float* __restrict__ v2, const float* __restrict__ b2,
                  const float* __restrict__ We1, const float* __restrict__ be1,
                  const float* __restrict__ We2, const float* __restrict__ be2,
                  float* __restrict__ out, int n) {
    __shared__ float sW1[64 * 64], sW2[64 * 64], sb1[64], sb2[64];
    __shared__ float srow[4][64], strow[4][64];
    for (int i = threadIdx.x; i < 64 * 64; i += 256) { sW1[i] = We1[i]; sW2[i] = We2[i]; }
    if (threadIdx.x < 64) { sb1[threadIdx.x] = be1[threadIdx.x]; sb2[threadIdx.x] = be2[threadIdx.x]; }
    __syncthreads();
    int wave = threadIdx.x >> 6, lane = threadIdx.x & 63;
    int node = blockIdx.x * 4 + wave;
    if (node >= n) return;
    float v = v2[(size_t)node * 64 + lane] + b2[lane];
    float m = v;
    #pragma unroll
    for (int o = 32; o; o >>= 1) m = fmaxf(m, __shfl_xor(m, o));
    float p = expf(v - m);
    float s = p;
    #pragma unroll
    for (int o = 32; o; o >>= 1) s += __shfl_xor(s, o);
    float ls = v - m - logf(s);
    srow[wave][lane] = ls;
    float acc = sb1[lane];
    #pragma unroll 8
    for (int k = 0; k < 64; k++) acc += srow[wave][k] * sW1[k * 64 + lane];
    float t = acc > 0.f ? acc : 0.f;
    strow[wave][lane] = t;
    acc = sb2[lane];
    #pragma unroll 8
    for (int k = 0; k < 64; k++) acc += strow[wave][k] * sW2[k * 64 + lane];
    float g = 1.f / (1.f + expf(-acc));
    out[(size_t)node * 64 + lane] = ls + g;
}

extern "C" void kernel_launch(void* const* d_in, const int* in_sizes, int n_in,
                              void* d_out, int out_size, void* d_ws, size_t ws_size,
                              hipStream_t stream) {
    const float* x    = (const float*)d_in[0];
    const int*   ei   = (const int*)d_in[1];
    const float* Wl1  = (const float*)d_in[2];
    const float* Wr1  = (const float*)d_in[3];
    const float* att1 = (const float*)d_in[4];
    const float* b1   = (const float*)d_in[5];
    const float* Wl2  = (const float*)d_in[6];
    const float* Wr2  = (const float*)d_in[7];
    const float* att2 = (const float*)d_in[8];
    const float* b2   = (const float*)d_in[9];
    const float* We1  = (const float*)d_in[10];
    const float* be1  = (const float*)d_in[11];
    const float* We2  = (const float*)d_in[12];
    const float* be2  = (const float*)d_in[13];
    float* out = (float*)d_out;

    const int n  = in_sizes[0] / 128;
    const int E  = in_sizes[1] / 2;
    const int ET = E + n;
    const int nchunks = (n + 1023) / 1024;

    float* ws = (float*)d_ws;
    size_t o = 0;
    float* xl1 = ws + o; o += (size_t)n * 128;   // later: xl2 [n,64] + xr2 [n,64]
    float* xr1 = ws + o; o += (size_t)n * 128;   // later: v2 [n,64]
    float* h1  = ws + o; o += (size_t)n * 128;
    int* rowptr   = (int*)(ws + o); o += (size_t)(n + 1);
    int* cursor   = (int*)(ws + o); o += (size_t)n;
    int* srcs     = (int*)(ws + o); o += (size_t)ET;
    int* partials = (int*)(ws + o); o += 1024;
    float* xl2 = xl1;
    float* xr2 = xl1 + (size_t)n * 64;
    float* v2  = xr1;
    int* deg = cursor;  // deg reuses cursor pre-scan; cursor rebuilt by scan_apply

    const int BS = 256;
    auto blocks = [](long long t, int bs) { return (int)((t + bs - 1) / bs); };

    // ---- CSR build (by dst), self-loops via deg init = 1 ----
    fill_int_kernel<<<blocks(n, BS), BS, 0, stream>>>(deg, 1, n);
    hist_kernel<<<blocks(E, BS), BS, 0, stream>>>(ei, deg, E);
    scan_block_kernel<<<nchunks, 1024, 0, stream>>>(deg, rowptr, partials, n);
    scan_partials_kernel<<<1, 1024, 0, stream>>>(partials, nchunks);
    scan_apply_kernel<<<nchunks, 1024, 0, stream>>>(rowptr, partials, cursor, n);
    scatter_kernel<<<blocks(ET, BS), BS, 0, stream>>>(ei, cursor, srcs, E, ET);

    // ---- layer 1 ----
    gemm_dual_kernel<256><<<blocks(n, 64), BS, 0, stream>>>(x, Wl1, Wr1, xl1, xr1, n);
    node_agg_kernel<2, true><<<blocks((long long)n * 2 * 16, BS), BS, 0, stream>>>(
        xl1, xr1, rowptr, srcs, att1, b1, h1, n);

    // ---- layer 2 ----
    gemm_dual_kernel<128><<<blocks(n, 64), BS, 0, stream>>>(h1, Wl2, Wr2, xl2, xr2, n);
    node_agg_kernel<1, false><<<blocks((long long)n * 16, BS), BS, 0, stream>>>(
        xl2, xr2, rowptr, srcs, att2, nullptr, v2, n);

    // ---- finalize: bias + log_softmax + rule net ----
    final_kernel<<<blocks(((long long)n + 3) / 4 * 256, BS), BS, 0, stream>>>(
        v2, b2, We1, be1, We2, be2, out, n);
}

// Round 4
// 370.026 us; speedup vs baseline: 8.2153x; 1.1555x over previous
//
#include <hip/hip_runtime.h>
#include <hip/hip_bf16.h>
#include <math.h>

// ---------------------------------------------------------------------------
// GATv2 x2 + log_softmax + gated rule-net.
// R3: GEMM inner loop made vector-width in LDS: transposed X tile (a-frag =
// 2x ds_read_b128 broadcast), contiguous per-thread cols (b-frag = b128),
// 4 LDS instr : 64 FMA per k-step (was 16 scalar b32 : 64).
// ---------------------------------------------------------------------------

__global__ void fill_int_kernel(int* __restrict__ p, int v, int count) {
    int i = blockIdx.x * blockDim.x + threadIdx.x;
    if (i < count) p[i] = v;
}

__global__ void hist_kernel(const int* __restrict__ ei, int* __restrict__ deg, int E) {
    int e = blockIdx.x * blockDim.x + threadIdx.x;
    if (e < E) atomicAdd(&deg[ei[E + e]], 1);
}

__global__ __launch_bounds__(1024)
void scan_block_kernel(const int* __restrict__ deg, int* __restrict__ rowptr,
                       int* __restrict__ partials, int n) {
    __shared__ int s[1024];
    int i = blockIdx.x * 1024 + threadIdx.x;
    int v = (i < n) ? deg[i] : 0;
    s[threadIdx.x] = v;
    __syncthreads();
    #pragma unroll
    for (int off = 1; off < 1024; off <<= 1) {
        int t = (threadIdx.x >= off) ? s[threadIdx.x - off] : 0;
        __syncthreads();
        s[threadIdx.x] += t;
        __syncthreads();
    }
    if (i < n) rowptr[i + 1] = s[threadIdx.x];
    if (threadIdx.x == 1023) partials[blockIdx.x] = s[1023];
}

__global__ __launch_bounds__(1024)
void scan_partials_kernel(int* __restrict__ partials, int nparts) {
    __shared__ int s[1024];
    int v = (threadIdx.x < nparts) ? partials[threadIdx.x] : 0;
    s[threadIdx.x] = v;
    __syncthreads();
    #pragma unroll
    for (int off = 1; off < 1024; off <<= 1) {
        int t = (threadIdx.x >= off) ? s[threadIdx.x - off] : 0;
        __syncthreads();
        s[threadIdx.x] += t;
        __syncthreads();
    }
    if (threadIdx.x < nparts) partials[threadIdx.x] = s[threadIdx.x] - v;  // exclusive
}

__global__ __launch_bounds__(1024)
void scan_apply_kernel(int* __restrict__ rowptr, const int* __restrict__ partials,
                       int* __restrict__ cursor, int n) {
    int i = blockIdx.x * 1024 + threadIdx.x;
    if (i == 0) { rowptr[0] = 0; cursor[0] = 0; }
    if (i < n) {
        int val = rowptr[i + 1] + partials[blockIdx.x];
        rowptr[i + 1] = val;
        if (i + 1 < n) cursor[i + 1] = val;
    }
}

__global__ void scatter_kernel(const int* __restrict__ ei, int* __restrict__ cursor,
                               int* __restrict__ srcs, int E, int ET) {
    int e = blockIdx.x * blockDim.x + threadIdx.x;
    if (e >= ET) return;
    int src, dst;
    if (e < E) { src = ei[e]; dst = ei[E + e]; }
    else       { src = dst = e - E; }
    int pos = atomicAdd(&cursor[dst], 1);
    srcs[pos] = src;
}

// Fused dual GEMM: Y0[n,M]=X@W0, Y1[n,M]=X@W1 (M=MTOT/2), K=128.
// Block: 64 rows x MTOT cols, 256 threads, thread tile 8 rows x NJ cols.
// sXT transposed (k-major) so a-frag is 2x b128 broadcast; cols contiguous
// per thread so b-frag is b128 over contiguous dwords.
template<int MTOT>
__global__ __launch_bounds__(256)
void gemm_dual_kernel(const float* __restrict__ X,
                      const float* __restrict__ W0, const float* __restrict__ W1,
                      float* __restrict__ Y0, float* __restrict__ Y1, int n) {
    constexpr int K = 128, BK = 32, BM = 64;
    constexpr int M = MTOT / 2;
    constexpr int NJ = MTOT / 32;
    constexpr int NB = NJ / 4;           // float4 col-blocks per thread
    __shared__ float sXT[BK][68];        // [k][row], stride 68 (272B, 16B-aligned)
    __shared__ float sW[BK][MTOT];
    int tid = threadIdx.x;
    int cc = tid & 31, rr = tid >> 5;
    int row0 = blockIdx.x * BM;
    float acc[8][NJ];
    #pragma unroll
    for (int i = 0; i < 8; i++)
        #pragma unroll
        for (int j = 0; j < NJ; j++) acc[i][j] = 0.f;

    for (int kc = 0; kc < K / BK; ++kc) {
        // stage X tile transposed: global float4 along k -> 4 scalar LDS writes
        #pragma unroll
        for (int t = tid; t < BM * BK / 4; t += 256) {
            int r = t >> 3, c4 = t & 7;
            int grow = row0 + r;
            float4 v = (grow < n) ? *(const float4*)(X + (size_t)grow * K + kc * BK + c4 * 4)
                                  : make_float4(0.f, 0.f, 0.f, 0.f);
            sXT[c4 * 4 + 0][r] = v.x;
            sXT[c4 * 4 + 1][r] = v.y;
            sXT[c4 * 4 + 2][r] = v.z;
            sXT[c4 * 4 + 3][r] = v.w;
        }
        // stage W tile [BK][MTOT] = [W0 | W1], b128 in/out
        #pragma unroll
        for (int t = tid; t < BK * MTOT / 4; t += 256) {
            int kr = t / (MTOT / 4), m4 = t % (MTOT / 4);
            int m = m4 * 4, gk = kc * BK + kr;
            float4 v = (m < M) ? *(const float4*)(W0 + (size_t)gk * M + m)
                               : *(const float4*)(W1 + (size_t)gk * M + (m - M));
            *(float4*)(&sW[kr][m]) = v;
        }
        __syncthreads();
        #pragma unroll 8
        for (int k = 0; k < BK; ++k) {
            float4 a0 = *(const float4*)(&sXT[k][rr * 8]);
            float4 a1 = *(const float4*)(&sXT[k][rr * 8 + 4]);
            float a[8] = {a0.x, a0.y, a0.z, a0.w, a1.x, a1.y, a1.z, a1.w};
            float b[NJ];
            #pragma unroll
            for (int q = 0; q < NB; ++q) {
                float4 bv = *(const float4*)(&sW[k][q * 128 + cc * 4]);
                b[q * 4 + 0] = bv.x; b[q * 4 + 1] = bv.y;
                b[q * 4 + 2] = bv.z; b[q * 4 + 3] = bv.w;
            }
            #pragma unroll
            for (int i = 0; i < 8; i++)
                #pragma unroll
                for (int j = 0; j < NJ; j++) acc[i][j] += a[i] * b[j];
        }
        __syncthreads();
    }
    #pragma unroll
    for (int i = 0; i < 8; i++) {
        int row = row0 + rr * 8 + i;
        if (row >= n) continue;
        #pragma unroll
        for (int q = 0; q < NB; ++q) {
            int col = q * 128 + cc * 4;
            float4 v = make_float4(acc[i][q * 4], acc[i][q * 4 + 1],
                                   acc[i][q * 4 + 2], acc[i][q * 4 + 3]);
            if (col < M) *(float4*)(Y0 + (size_t)row * M + col) = v;
            else         *(float4*)(Y1 + (size_t)row * M + (col - M)) = v;
        }
    }
}

// One 16-lane group per (node, head): online softmax over incoming edges.
template<int H, bool RELU_BIAS>
__global__ __launch_bounds__(256)
void node_agg_kernel(const float* __restrict__ xl, const float* __restrict__ xr,
                     const int* __restrict__ rowptr, const int* __restrict__ srcs,
                     const float* __restrict__ att, const float* __restrict__ bias,
                     float* __restrict__ out, int n) {
    int g = (blockIdx.x * blockDim.x + threadIdx.x) >> 4;
    int lane = threadIdx.x & 15;
    if (g >= n * H) return;
    int node = g / H, head = g % H;
    const int HC = H * 64;
    int cbase = head * 64 + lane * 4;
    float4 r4 = *(const float4*)(xr + (size_t)node * HC + cbase);
    float4 a4 = *(const float4*)(att + cbase);
    int start = rowptr[node], end = rowptr[node + 1];
    float m = -INFINITY, d = 0.f;
    float4 acc = make_float4(0.f, 0.f, 0.f, 0.f);
    for (int k = start; k < end; ++k) {
        int src = srcs[k];
        float4 l4 = *(const float4*)(xl + (size_t)src * HC + cbase);
        float e, p = 0.f;
        e = l4.x + r4.x; e = e > 0.f ? e : 0.2f * e; p += e * a4.x;
        e = l4.y + r4.y; e = e > 0.f ? e : 0.2f * e; p += e * a4.y;
        e = l4.z + r4.z; e = e > 0.f ? e : 0.2f * e; p += e * a4.z;
        e = l4.w + r4.w; e = e > 0.f ? e : 0.2f * e; p += e * a4.w;
        #pragma unroll
        for (int o = 8; o; o >>= 1) p += __shfl_xor(p, o, 16);
        float nm = fmaxf(m, p);
        float sc = __expf(m - nm);
        float w  = __expf(p - nm);
        d = d * sc + w;
        acc.x = acc.x * sc + w * l4.x;
        acc.y = acc.y * sc + w * l4.y;
        acc.z = acc.z * sc + w * l4.z;
        acc.w = acc.w * sc + w * l4.w;
        m = nm;
    }
    float inv = 1.f / (d + 1e-16f);
    float4 o4 = make_float4(acc.x * inv, acc.y * inv, acc.z * inv, acc.w * inv);
    if (RELU_BIAS) {
        float4 b4 = *(const float4*)(bias + cbase);
        o4.x = fmaxf(o4.x + b4.x, 0.f);
        o4.y = fmaxf(o4.y + b4.y, 0.f);
        o4.z = fmaxf(o4.z + b4.z, 0.f);
        o4.w = fmaxf(o4.w + b4.w, 0.f);
    }
    *(float4*)(out + (size_t)node * HC + cbase) = o4;
}

// One wave per node: v2+bias -> log_softmax -> rule net -> out
__global__ __launch_bounds__(256)
void final_kernel(const float* __restrict__ v2, const float* __restrict__ b2,
                  const float* __restrict__ We1, const float* __restrict__ be1,
                  const float* __restrict__ We2, const float* __restrict__ be2,
                  float* __restrict__ out, int n) {
    __shared__ float sW1[64 * 64], sW2[64 * 64], sb1[64], sb2[64];
    __shared__ float srow[4][64], strow[4][64];
    for (int i = threadIdx.x; i < 64 * 64; i += 256) { sW1[i] = We1[i]; sW2[i] = We2[i]; }
    if (threadIdx.x < 64) { sb1[threadIdx.x] = be1[threadIdx.x]; sb2[threadIdx.x] = be2[threadIdx.x]; }
    __syncthreads();
    int wave = threadIdx.x >> 6, lane = threadIdx.x & 63;
    int node = blockIdx.x * 4 + wave;
    if (node >= n) return;
    float v = v2[(size_t)node * 64 + lane] + b2[lane];
    float m = v;
    #pragma unroll
    for (int o = 32; o; o >>= 1) m = fmaxf(m, __shfl_xor(m, o));
    float p = expf(v - m);
    float s = p;
    #pragma unroll
    for (int o = 32; o; o >>= 1) s += __shfl_xor(s, o);
    float ls = v - m - logf(s);
    srow[wave][lane] = ls;
    float acc = sb1[lane];
    #pragma unroll 8
    for (int k = 0; k < 64; k++) acc += srow[wave][k] * sW1[k * 64 + lane];
    float t = acc > 0.f ? acc : 0.f;
    strow[wave][lane] = t;
    acc = sb2[lane];
    #pragma unroll 8
    for (int k = 0; k < 64; k++) acc += strow[wave][k] * sW2[k * 64 + lane];
    float g = 1.f / (1.f + expf(-acc));
    out[(size_t)node * 64 + lane] = ls + g;
}

extern "C" void kernel_launch(void* const* d_in, const int* in_sizes, int n_in,
                              void* d_out, int out_size, void* d_ws, size_t ws_size,
                              hipStream_t stream) {
    const float* x    = (const float*)d_in[0];
    const int*   ei   = (const int*)d_in[1];
    const float* Wl1  = (const float*)d_in[2];
    const float* Wr1  = (const float*)d_in[3];
    const float* att1 = (const float*)d_in[4];
    const float* b1   = (const float*)d_in[5];
    const float* Wl2  = (const float*)d_in[6];
    const float* Wr2  = (const float*)d_in[7];
    const float* att2 = (const float*)d_in[8];
    const float* b2   = (const float*)d_in[9];
    const float* We1  = (const float*)d_in[10];
    const float* be1  = (const float*)d_in[11];
    const float* We2  = (const float*)d_in[12];
    const float* be2  = (const float*)d_in[13];
    float* out = (float*)d_out;

    const int n  = in_sizes[0] / 128;
    const int E  = in_sizes[1] / 2;
    const int ET = E + n;
    const int nchunks = (n + 1023) / 1024;

    float* ws = (float*)d_ws;
    size_t o = 0;
    float* xl1 = ws + o; o += (size_t)n * 128;   // later: xl2 [n,64] + xr2 [n,64]
    float* xr1 = ws + o; o += (size_t)n * 128;   // later: v2 [n,64]
    float* h1  = ws + o; o += (size_t)n * 128;
    int* rowptr   = (int*)(ws + o); o += (size_t)(n + 1);
    int* cursor   = (int*)(ws + o); o += (size_t)n;
    int* srcs     = (int*)(ws + o); o += (size_t)ET;
    int* partials = (int*)(ws + o); o += 1024;
    float* xl2 = xl1;
    float* xr2 = xl1 + (size_t)n * 64;
    float* v2  = xr1;
    int* deg = cursor;  // deg reuses cursor pre-scan; cursor rebuilt by scan_apply

    const int BS = 256;
    auto blocks = [](long long t, int bs) { return (int)((t + bs - 1) / bs); };

    // ---- CSR build (by dst), self-loops via deg init = 1 ----
    fill_int_kernel<<<blocks(n, BS), BS, 0, stream>>>(deg, 1, n);
    hist_kernel<<<blocks(E, BS), BS, 0, stream>>>(ei, deg, E);
    scan_block_kernel<<<nchunks, 1024, 0, stream>>>(deg, rowptr, partials, n);
    scan_partials_kernel<<<1, 1024, 0, stream>>>(partials, nchunks);
    scan_apply_kernel<<<nchunks, 1024, 0, stream>>>(rowptr, partials, cursor, n);
    scatter_kernel<<<blocks(ET, BS), BS, 0, stream>>>(ei, cursor, srcs, E, ET);

    // ---- layer 1 ----
    gemm_dual_kernel<256><<<blocks(n, 64), BS, 0, stream>>>(x, Wl1, Wr1, xl1, xr1, n);
    node_agg_kernel<2, true><<<blocks((long long)n * 2 * 16, BS), BS, 0, stream>>>(
        xl1, xr1, rowptr, srcs, att1, b1, h1, n);

    // ---- layer 2 ----
    gemm_dual_kernel<128><<<blocks(n, 64), BS, 0, stream>>>(h1, Wl2, Wr2, xl2, xr2, n);
    node_agg_kernel<1, false><<<blocks((long long)n * 16, BS), BS, 0, stream>>>(
        xl2, xr2, rowptr, srcs, att2, nullptr, v2, n);

    // ---- finalize: bias + log_softmax + rule net ----
    final_kernel<<<blocks(((long long)n + 3) / 4 * 256, BS), BS, 0, stream>>>(
        v2, b2, We1, be1, We2, be2, out, n);
}

// Round 5
// 356.310 us; speedup vs baseline: 8.5316x; 1.0385x over previous
//
#include <hip/hip_runtime.h>
#include <hip/hip_bf16.h>
#include <hip/hip_fp16.h>
#include <math.h>

// ---------------------------------------------------------------------------
// GATv2 x2 + log_softmax + gated rule-net.
// R4: xl/xr feature tables stored fp16 (gather traffic halves; node_agg is
// random-gather-bytes-bound at ~2.5 TB/s). All arithmetic stays fp32.
// ---------------------------------------------------------------------------

__device__ inline float4 load_half4(const __half* p) {
    uint2 u = *(const uint2*)p;
    __half2 h01 = *(__half2*)&u.x;
    __half2 h23 = *(__half2*)&u.y;
    float2 f01 = __half22float2(h01);
    float2 f23 = __half22float2(h23);
    return make_float4(f01.x, f01.y, f23.x, f23.y);
}

__device__ inline void store_half4(__half* p, float a, float b, float c, float d) {
    __half2 h01 = __floats2half2_rn(a, b);
    __half2 h23 = __floats2half2_rn(c, d);
    uint2 u;
    u.x = *(unsigned int*)&h01;
    u.y = *(unsigned int*)&h23;
    *(uint2*)p = u;
}

__global__ void fill_int_kernel(int* __restrict__ p, int v, int count) {
    int i = blockIdx.x * blockDim.x + threadIdx.x;
    if (i < count) p[i] = v;
}

__global__ void hist_kernel(const int* __restrict__ ei, int* __restrict__ deg, int E) {
    int e = blockIdx.x * blockDim.x + threadIdx.x;
    if (e < E) atomicAdd(&deg[ei[E + e]], 1);
}

__global__ __launch_bounds__(1024)
void scan_block_kernel(const int* __restrict__ deg, int* __restrict__ rowptr,
                       int* __restrict__ partials, int n) {
    __shared__ int s[1024];
    int i = blockIdx.x * 1024 + threadIdx.x;
    int v = (i < n) ? deg[i] : 0;
    s[threadIdx.x] = v;
    __syncthreads();
    #pragma unroll
    for (int off = 1; off < 1024; off <<= 1) {
        int t = (threadIdx.x >= off) ? s[threadIdx.x - off] : 0;
        __syncthreads();
        s[threadIdx.x] += t;
        __syncthreads();
    }
    if (i < n) rowptr[i + 1] = s[threadIdx.x];
    if (threadIdx.x == 1023) partials[blockIdx.x] = s[1023];
}

__global__ __launch_bounds__(1024)
void scan_partials_kernel(int* __restrict__ partials, int nparts) {
    __shared__ int s[1024];
    int v = (threadIdx.x < nparts) ? partials[threadIdx.x] : 0;
    s[threadIdx.x] = v;
    __syncthreads();
    #pragma unroll
    for (int off = 1; off < 1024; off <<= 1) {
        int t = (threadIdx.x >= off) ? s[threadIdx.x - off] : 0;
        __syncthreads();
        s[threadIdx.x] += t;
        __syncthreads();
    }
    if (threadIdx.x < nparts) partials[threadIdx.x] = s[threadIdx.x] - v;  // exclusive
}

__global__ __launch_bounds__(1024)
void scan_apply_kernel(int* __restrict__ rowptr, const int* __restrict__ partials,
                       int* __restrict__ cursor, int n) {
    int i = blockIdx.x * 1024 + threadIdx.x;
    if (i == 0) { rowptr[0] = 0; cursor[0] = 0; }
    if (i < n) {
        int val = rowptr[i + 1] + partials[blockIdx.x];
        rowptr[i + 1] = val;
        if (i + 1 < n) cursor[i + 1] = val;
    }
}

__global__ void scatter_kernel(const int* __restrict__ ei, int* __restrict__ cursor,
                               int* __restrict__ srcs, int E, int ET) {
    int e = blockIdx.x * blockDim.x + threadIdx.x;
    if (e >= ET) return;
    int src, dst;
    if (e < E) { src = ei[e]; dst = ei[E + e]; }
    else       { src = dst = e - E; }
    int pos = atomicAdd(&cursor[dst], 1);
    srcs[pos] = src;
}

// Fused dual GEMM: Y0[n,M]=X@W0, Y1[n,M]=X@W1 (M=MTOT/2), K=128, fp16 output.
template<int MTOT>
__global__ __launch_bounds__(256)
void gemm_dual_kernel(const float* __restrict__ X,
                      const float* __restrict__ W0, const float* __restrict__ W1,
                      __half* __restrict__ Y0, __half* __restrict__ Y1, int n) {
    constexpr int K = 128, BK = 32, BM = 64;
    constexpr int M = MTOT / 2;
    constexpr int NJ = MTOT / 32;
    constexpr int NB = NJ / 4;
    __shared__ float sXT[BK][68];        // [k][row], transposed
    __shared__ float sW[BK][MTOT];
    int tid = threadIdx.x;
    int cc = tid & 31, rr = tid >> 5;
    int row0 = blockIdx.x * BM;
    float acc[8][NJ];
    #pragma unroll
    for (int i = 0; i < 8; i++)
        #pragma unroll
        for (int j = 0; j < NJ; j++) acc[i][j] = 0.f;

    for (int kc = 0; kc < K / BK; ++kc) {
        #pragma unroll
        for (int t = tid; t < BM * BK / 4; t += 256) {
            int r = t >> 3, c4 = t & 7;
            int grow = row0 + r;
            float4 v = (grow < n) ? *(const float4*)(X + (size_t)grow * K + kc * BK + c4 * 4)
                                  : make_float4(0.f, 0.f, 0.f, 0.f);
            sXT[c4 * 4 + 0][r] = v.x;
            sXT[c4 * 4 + 1][r] = v.y;
            sXT[c4 * 4 + 2][r] = v.z;
            sXT[c4 * 4 + 3][r] = v.w;
        }
        #pragma unroll
        for (int t = tid; t < BK * MTOT / 4; t += 256) {
            int kr = t / (MTOT / 4), m4 = t % (MTOT / 4);
            int m = m4 * 4, gk = kc * BK + kr;
            float4 v = (m < M) ? *(const float4*)(W0 + (size_t)gk * M + m)
                               : *(const float4*)(W1 + (size_t)gk * M + (m - M));
            *(float4*)(&sW[kr][m]) = v;
        }
        __syncthreads();
        #pragma unroll 8
        for (int k = 0; k < BK; ++k) {
            float4 a0 = *(const float4*)(&sXT[k][rr * 8]);
            float4 a1 = *(const float4*)(&sXT[k][rr * 8 + 4]);
            float a[8] = {a0.x, a0.y, a0.z, a0.w, a1.x, a1.y, a1.z, a1.w};
            float b[NJ];
            #pragma unroll
            for (int q = 0; q < NB; ++q) {
                float4 bv = *(const float4*)(&sW[k][q * 128 + cc * 4]);
                b[q * 4 + 0] = bv.x; b[q * 4 + 1] = bv.y;
                b[q * 4 + 2] = bv.z; b[q * 4 + 3] = bv.w;
            }
            #pragma unroll
            for (int i = 0; i < 8; i++)
                #pragma unroll
                for (int j = 0; j < NJ; j++) acc[i][j] += a[i] * b[j];
        }
        __syncthreads();
    }
    #pragma unroll
    for (int i = 0; i < 8; i++) {
        int row = row0 + rr * 8 + i;
        if (row >= n) continue;
        #pragma unroll
        for (int q = 0; q < NB; ++q) {
            int col = q * 128 + cc * 4;
            if (col < M)
                store_half4(Y0 + (size_t)row * M + col,
                            acc[i][q * 4], acc[i][q * 4 + 1], acc[i][q * 4 + 2], acc[i][q * 4 + 3]);
            else
                store_half4(Y1 + (size_t)row * M + (col - M),
                            acc[i][q * 4], acc[i][q * 4 + 1], acc[i][q * 4 + 2], acc[i][q * 4 + 3]);
        }
    }
}

// One 16-lane group per (node, head): online softmax over incoming edges.
// xl/xr are fp16 tables; all math fp32.
template<int H, bool RELU_BIAS>
__global__ __launch_bounds__(256)
void node_agg_kernel(const __half* __restrict__ xl, const __half* __restrict__ xr,
                     const int* __restrict__ rowptr, const int* __restrict__ srcs,
                     const float* __restrict__ att, const float* __restrict__ bias,
                     float* __restrict__ out, int n) {
    int g = (blockIdx.x * blockDim.x + threadIdx.x) >> 4;
    int lane = threadIdx.x & 15;
    if (g >= n * H) return;
    int node = g / H, head = g % H;
    const int HC = H * 64;
    int cbase = head * 64 + lane * 4;
    float4 r4 = load_half4(xr + (size_t)node * HC + cbase);
    float4 a4 = *(const float4*)(att + cbase);
    int start = rowptr[node], end = rowptr[node + 1];
    float m = -INFINITY, d = 0.f;
    float4 acc = make_float4(0.f, 0.f, 0.f, 0.f);
    for (int k = start; k < end; ++k) {
        int src = srcs[k];
        float4 l4 = load_half4(xl + (size_t)src * HC + cbase);
        float e, p = 0.f;
        e = l4.x + r4.x; e = e > 0.f ? e : 0.2f * e; p += e * a4.x;
        e = l4.y + r4.y; e = e > 0.f ? e : 0.2f * e; p += e * a4.y;
        e = l4.z + r4.z; e = e > 0.f ? e : 0.2f * e; p += e * a4.z;
        e = l4.w + r4.w; e = e > 0.f ? e : 0.2f * e; p += e * a4.w;
        #pragma unroll
        for (int o = 8; o; o >>= 1) p += __shfl_xor(p, o, 16);
        float nm = fmaxf(m, p);
        float sc = __expf(m - nm);
        float w  = __expf(p - nm);
        d = d * sc + w;
        acc.x = acc.x * sc + w * l4.x;
        acc.y = acc.y * sc + w * l4.y;
        acc.z = acc.z * sc + w * l4.z;
        acc.w = acc.w * sc + w * l4.w;
        m = nm;
    }
    float inv = 1.f / (d + 1e-16f);
    float4 o4 = make_float4(acc.x * inv, acc.y * inv, acc.z * inv, acc.w * inv);
    if (RELU_BIAS) {
        float4 b4 = *(const float4*)(bias + cbase);
        o4.x = fmaxf(o4.x + b4.x, 0.f);
        o4.y = fmaxf(o4.y + b4.y, 0.f);
        o4.z = fmaxf(o4.z + b4.z, 0.f);
        o4.w = fmaxf(o4.w + b4.w, 0.f);
    }
    *(float4*)(out + (size_t)node * HC + cbase) = o4;
}

// One wave per node: v2+bias -> log_softmax -> rule net -> out
__global__ __launch_bounds__(256)
void final_kernel(const float* __restrict__ v2, const float* __restrict__ b2,
                  const float* __restrict__ We1, const float* __restrict__ be1,
                  const float* __restrict__ We2, const float* __restrict__ be2,
                  float* __restrict__ out, int n) {
    __shared__ float sW1[64 * 64], sW2[64 * 64], sb1[64], sb2[64];
    __shared__ float srow[4][64], strow[4][64];
    for (int i = threadIdx.x; i < 64 * 64; i += 256) { sW1[i] = We1[i]; sW2[i] = We2[i]; }
    if (threadIdx.x < 64) { sb1[threadIdx.x] = be1[threadIdx.x]; sb2[threadIdx.x] = be2[threadIdx.x]; }
    __syncthreads();
    int wave = threadIdx.x >> 6, lane = threadIdx.x & 63;
    int node = blockIdx.x * 4 + wave;
    if (node >= n) return;
    float v = v2[(size_t)node * 64 + lane] + b2[lane];
    float m = v;
    #pragma unroll
    for (int o = 32; o; o >>= 1) m = fmaxf(m, __shfl_xor(m, o));
    float p = expf(v - m);
    float s = p;
    #pragma unroll
    for (int o = 32; o; o >>= 1) s += __shfl_xor(s, o);
    float ls = v - m - logf(s);
    srow[wave][lane] = ls;
    float acc = sb1[lane];
    #pragma unroll 8
    for (int k = 0; k < 64; k++) acc += srow[wave][k] * sW1[k * 64 + lane];
    float t = acc > 0.f ? acc : 0.f;
    strow[wave][lane] = t;
    acc = sb2[lane];
    #pragma unroll 8
    for (int k = 0; k < 64; k++) acc += strow[wave][k] * sW2[k * 64 + lane];
    float g = 1.f / (1.f + expf(-acc));
    out[(size_t)node * 64 + lane] = ls + g;
}

extern "C" void kernel_launch(void* const* d_in, const int* in_sizes, int n_in,
                              void* d_out, int out_size, void* d_ws, size_t ws_size,
                              hipStream_t stream) {
    const float* x    = (const float*)d_in[0];
    const int*   ei   = (const int*)d_in[1];
    const float* Wl1  = (const float*)d_in[2];
    const float* Wr1  = (const float*)d_in[3];
    const float* att1 = (const float*)d_in[4];
    const float* b1   = (const float*)d_in[5];
    const float* Wl2  = (const float*)d_in[6];
    const float* Wr2  = (const float*)d_in[7];
    const float* att2 = (const float*)d_in[8];
    const float* b2   = (const float*)d_in[9];
    const float* We1  = (const float*)d_in[10];
    const float* be1  = (const float*)d_in[11];
    const float* We2  = (const float*)d_in[12];
    const float* be2  = (const float*)d_in[13];
    float* out = (float*)d_out;

    const int n  = in_sizes[0] / 128;
    const int E  = in_sizes[1] / 2;
    const int ET = E + n;
    const int nchunks = (n + 1023) / 1024;

    float* ws = (float*)d_ws;
    size_t o = 0;
    __half* xl1 = (__half*)(ws + o); o += (size_t)n * 64;   // n*128 halves
    __half* xr1 = (__half*)(ws + o); o += (size_t)n * 64;   // n*128 halves
    float*  h1  = ws + o;            o += (size_t)n * 128;
    float*  v2  = ws + o;            o += (size_t)n * 64;
    int* rowptr   = (int*)(ws + o); o += (size_t)(n + 1);
    int* cursor   = (int*)(ws + o); o += (size_t)n;
    int* srcs     = (int*)(ws + o); o += (size_t)ET;
    int* partials = (int*)(ws + o); o += 1024;
    // layer-2 fp16 tables reuse layer-1 table space (dead by then)
    __half* xl2 = xl1;                          // n*64 halves
    __half* xr2 = xl1 + (size_t)n * 64;         // n*64 halves
    int* deg = cursor;  // deg reuses cursor pre-scan; cursor rebuilt by scan_apply

    const int BS = 256;
    auto blocks = [](long long t, int bs) { return (int)((t + bs - 1) / bs); };

    // ---- CSR build (by dst), self-loops via deg init = 1 ----
    fill_int_kernel<<<blocks(n, BS), BS, 0, stream>>>(deg, 1, n);
    hist_kernel<<<blocks(E, BS), BS, 0, stream>>>(ei, deg, E);
    scan_block_kernel<<<nchunks, 1024, 0, stream>>>(deg, rowptr, partials, n);
    scan_partials_kernel<<<1, 1024, 0, stream>>>(partials, nchunks);
    scan_apply_kernel<<<nchunks, 1024, 0, stream>>>(rowptr, partials, cursor, n);
    scatter_kernel<<<blocks(ET, BS), BS, 0, stream>>>(ei, cursor, srcs, E, ET);

    // ---- layer 1 ----
    gemm_dual_kernel<256><<<blocks(n, 64), BS, 0, stream>>>(x, Wl1, Wr1, xl1, xr1, n);
    node_agg_kernel<2, true><<<blocks((long long)n * 2 * 16, BS), BS, 0, stream>>>(
        xl1, xr1, rowptr, srcs, att1, b1, h1, n);

    // ---- layer 2 ----
    gemm_dual_kernel<128><<<blocks(n, 64), BS, 0, stream>>>(h1, Wl2, Wr2, xl2, xr2, n);
    node_agg_kernel<1, false><<<blocks((long long)n * 16, BS), BS, 0, stream>>>(
        xl2, xr2, rowptr, srcs, att2, nullptr, v2, n);

    // ---- finalize: bias + log_softmax + rule net ----
    final_kernel<<<blocks(((long long)n + 3) / 4 * 256, BS), BS, 0, stream>>>(
        v2, b2, We1, be1, We2, be2, out, n);
}